// Round 19
// baseline (334.572 us; speedup 1.0000x reference)
//
#include <hip/hip_runtime.h>

#define BB 32
#define TT 243
#define JJ 17
#define CC 256
#define BJC (BB*JJ)          // 544
#define MM (BJC*TT)          // 132192 rows (compact: r = bj*TT + t)
#define FR (BJC*256)         // 139264 padded flat rows: flat = bj*256 + t
#define NEG_INF (-3.0e38f)

typedef __attribute__((ext_vector_type(8))) short bf16x8;
typedef __attribute__((ext_vector_type(4))) float f32x4;
typedef __attribute__((ext_vector_type(8))) _Float16 f16x8;
typedef __attribute__((ext_vector_type(4))) _Float16 f16x4;

__device__ __forceinline__ unsigned short f2bf(float f) {
  unsigned int u = __float_as_uint(f);
  u = (u + 0x7fffu + ((u >> 16) & 1u)) >> 16;   // RNE
  return (unsigned short)u;
}
__device__ __forceinline__ float bf2f(unsigned short s) {
  return __uint_as_float(((unsigned int)s) << 16);
}

// async global->LDS, 16B per lane: lds dest = uniform base + lane*16
__device__ __forceinline__ void gld16(const void* g, void* l) {
  __builtin_amdgcn_global_load_lds(
      (__attribute__((address_space(1))) void*)(g),
      (__attribute__((address_space(3))) void*)(l), 16, 0, 0);
}

// ---------- K0a: W_u,W_v f32 [C,C] -> wcp f16 [4 ksteps][512][64] (swizzled) ----------
__launch_bounds__(256)
__global__ void k_prep_w(const float* __restrict__ Wu, const float* __restrict__ Wv,
                         _Float16* __restrict__ wcp) {
  const int r = blockIdx.x * 4 + (threadIdx.x >> 6);   // 0..511
  const int l = threadIdx.x & 63;
  const float* src = ((r < CC) ? (Wu + (size_t)r * CC) : (Wv + (size_t)(r - CC) * CC)) + l * 4;
  float4 v = *reinterpret_cast<const float4*>(src);
  f16x4 hv = (f16x4){(_Float16)v.x, (_Float16)v.y, (_Float16)v.z, (_Float16)v.w};
  const int ks = l >> 4;                 // k-plane 0..3 (64 f16 each)
  const int u  = (l & 15) >> 1;          // 16B unit 0..7
  const int s  = u ^ (r & 7);            // bank swizzle slot
  *reinterpret_cast<f16x4*>(wcp + ((size_t)ks * 512 + r) * 64 + s * 8 + (l & 1) * 4) = hv;
}

// ---------- K0b: x -> xqh/xql (f16 hi + residual lo), panel-padded flat layout ----------
__launch_bounds__(256)
__global__ void k_prep_x(const float* __restrict__ x,
                         _Float16* __restrict__ xqh, _Float16* __restrict__ xql) {
  const int r = blockIdx.x * 4 + (threadIdx.x >> 6);   // compact row 0..MM-1
  const int l = threadIdx.x & 63;
  const int bj = r / TT, t = r - bj * TT;
  const int b = bj / JJ, j = bj - b * JJ;
  float4 v = *reinterpret_cast<const float4*>(
      x + ((size_t)(b * TT + t) * JJ + j) * CC + l * 4);
  _Float16 h0 = (_Float16)v.x, h1 = (_Float16)v.y, h2 = (_Float16)v.z, h3 = (_Float16)v.w;
  f16x4 hv = (f16x4){h0, h1, h2, h3};
  f16x4 lv = (f16x4){(_Float16)(v.x - (float)h0), (_Float16)(v.y - (float)h1),
                     (_Float16)(v.z - (float)h2), (_Float16)(v.w - (float)h3)};
  const int fr = bj * 256 + t;            // padded flat row
  const int ks = l >> 4;
  const int u  = (l & 15) >> 1;
  const int s  = u ^ (t & 7);             // == fr&7 since bj*256 % 8 == 0
  const size_t off = ((size_t)ks * FR + fr) * 64 + s * 8 + (l & 1) * 4;
  *reinterpret_cast<f16x4*>(xqh + off) = hv;
  *reinterpret_cast<f16x4*>(xql + off) = lv;
}

// ---------- K2: sim + top-k fused, per bj row-half block (XCD-paired) ----------
// Pass-major MFMA order: all hh, then hl, then lh -> 16 independent MFMAs
// between accumulator reuses (was 3 dependent back-to-back). Per-accumulator
// order hh->hl->lh preserved -> bitwise identical results.
__launch_bounds__(512, 4)
__global__ void k_sim(const _Float16* __restrict__ xqh, const _Float16* __restrict__ xql,
                      float* __restrict__ dis_o,
                      unsigned long long* __restrict__ mask_o,
                      unsigned char* __restrict__ nbr_o,
                      unsigned char* __restrict__ deg_o) {
  __shared__ __align__(16) char LB[65536];
  _Float16* Sh = (_Float16*)LB;                 // 32 KB
  _Float16* Sl = (_Float16*)(LB + 32768);       // 32 KB
  const int bid = blockIdx.x;
  const int g = bid >> 4, s_ = bid & 15;
  const int bj = g * 8 + (s_ & 7);              // 544 = 68*8 -> bijective
  const int rh = s_ >> 3;                       // row half 0/1
  const int tid = threadIdx.x, lane = tid & 63, wid = tid >> 6;
  const int wr = wid >> 2, wc = wid & 3;        // wave tile: 64 rows x 64 cols
  const int rowbase = rh * 128 + wr * 64;
  const int l15 = lane & 15, lg = lane >> 4;
  const size_t rb = (size_t)bj * 256;
  const size_t lsrc = (size_t)(lane >> 3) * 64 + (lane & 7) * 8;

  // LDS element offsets are k-step invariant; kh toggles ^32 (see swizzle alg.)
  const int ra0 = rowbase + l15;
  const int ca0 = wc * 64 + l15;
  const int offA0 = ra0 * 64 + (lg ^ (ra0 & 7)) * 8;   // + i*1024
  const int offB0 = ca0 * 64 + (lg ^ (ca0 & 7)) * 8;   // + j*1024

  f32x4 acc[4][4];
  #pragma unroll
  for (int i = 0; i < 4; i++)
    #pragma unroll
    for (int j = 0; j < 4; j++) acc[i][j] = (f32x4){0.f, 0.f, 0.f, 0.f};

  for (int ks = 0; ks < 4; ++ks) {
    {
      const _Float16* ph = xqh + ((size_t)ks * FR + rb) * 64;
      const _Float16* pl = xql + ((size_t)ks * FR + rb) * 64;
      #pragma unroll
      for (int c = 0; c < 4; ++c) {
        const int row0 = (wid * 4 + c) * 8;
        gld16(ph + (size_t)row0 * 64 + lsrc, Sh + row0 * 64);
        gld16(pl + (size_t)row0 * 64 + lsrc, Sl + row0 * 64);
      }
    }
    __syncthreads();
    #pragma unroll
    for (int kh = 0; kh < 2; ++kh) {
      const int kx = kh ? 32 : 0;
      f16x8 ah[4], al[4], bh[4], bl[4];
      #pragma unroll
      for (int j = 0; j < 4; ++j) {
        bh[j] = *reinterpret_cast<const f16x8*>(&Sh[(offB0 + j * 1024) ^ kx]);
        bl[j] = *reinterpret_cast<const f16x8*>(&Sl[(offB0 + j * 1024) ^ kx]);
      }
      #pragma unroll
      for (int i = 0; i < 4; ++i) {
        ah[i] = *reinterpret_cast<const f16x8*>(&Sh[(offA0 + i * 1024) ^ kx]);
        al[i] = *reinterpret_cast<const f16x8*>(&Sl[(offA0 + i * 1024) ^ kx]);
      }
      #pragma unroll
      for (int i = 0; i < 4; ++i)
        #pragma unroll
        for (int j = 0; j < 4; ++j)
          acc[i][j] = __builtin_amdgcn_mfma_f32_16x16x32_f16(ah[i], bh[j], acc[i][j], 0, 0, 0);
      #pragma unroll
      for (int i = 0; i < 4; ++i)
        #pragma unroll
        for (int j = 0; j < 4; ++j)
          acc[i][j] = __builtin_amdgcn_mfma_f32_16x16x32_f16(ah[i], bl[j], acc[i][j], 0, 0, 0);
      #pragma unroll
      for (int i = 0; i < 4; ++i)
        #pragma unroll
        for (int j = 0; j < 4; ++j)
          acc[i][j] = __builtin_amdgcn_mfma_f32_16x16x32_f16(al[i], bh[j], acc[i][j], 0, 0, 0);
    }
    __syncthreads();                            // also frees LB for the epilogue
  }

  // ---- fused top-k epilogue ----
  float* top4 = (float*)LB;                              // [128][4 wc][4]  8 KB
  unsigned long long* mlds = (unsigned long long*)(LB + 8192);  // [128][4]  4 KB
  float* thrl = (float*)(LB + 8192 + 4096);              // [128]           512 B

  auto mval = [&](int i, int j, int q) -> float {
    float x = acc[i][j][q];
    if (wc == 3 && j == 3 && l15 >= 3) x = NEG_INF;
    return x;
  };

  // (1) per-wave top-4 per row
  #pragma unroll
  for (int i = 0; i < 4; ++i) {
    #pragma unroll
    for (int q = 0; q < 4; ++q) {
      float v0 = mval(i, 0, q), v1 = mval(i, 1, q),
            v2 = mval(i, 2, q), v3 = mval(i, 3, q);
      { float mx, mn;
        mx=fmaxf(v0,v1); mn=fminf(v0,v1); v0=mx; v1=mn;
        mx=fmaxf(v2,v3); mn=fminf(v2,v3); v2=mx; v3=mn;
        mx=fmaxf(v0,v2); mn=fminf(v0,v2); v0=mx; v2=mn;
        mx=fmaxf(v1,v3); mn=fminf(v1,v3); v1=mx; v3=mn;
        mx=fmaxf(v1,v2); mn=fminf(v1,v2); v1=mx; v2=mn; }
      #pragma unroll
      for (int off = 1; off < 16; off <<= 1) {   // 16-lane butterfly
        float b0 = __shfl_xor(v0, off), b1 = __shfl_xor(v1, off),
              b2 = __shfl_xor(v2, off), b3 = __shfl_xor(v3, off);
        float t0 = fmaxf(v0, b3), t1 = fmaxf(v1, b2),
              t2 = fmaxf(v2, b1), t3 = fmaxf(v3, b0);
        float mx, mn;
        mx=fmaxf(t0,t2); mn=fminf(t0,t2); t0=mx; t2=mn;
        mx=fmaxf(t1,t3); mn=fminf(t1,t3); t1=mx; t3=mn;
        mx=fmaxf(t0,t1); mn=fminf(t0,t1); t0=mx; t1=mn;
        mx=fmaxf(t2,t3); mn=fminf(t2,t3); t2=mx; t3=mn;
        v0=t0; v1=t1; v2=t2; v3=t3;
      }
      if (l15 == 0) {
        int rloc = wr * 64 + i * 16 + lg * 4 + q;
        float* d = &top4[(rloc * 4 + wc) * 4];
        d[0] = v0; d[1] = v1; d[2] = v2; d[3] = v3;
      }
    }
  }
  __syncthreads();

  // (2) merge 4 wave-quads -> thr per row
  if (tid < 128) {
    float t0 = NEG_INF, t1 = NEG_INF, t2 = NEG_INF, t3 = NEG_INF;
    #pragma unroll
    for (int w = 0; w < 4; ++w) {
      #pragma unroll
      for (int e = 0; e < 4; ++e) {
        float xv = top4[(tid * 4 + w) * 4 + e];
        if (xv > t3) {
          if (xv > t0)      { t3 = t2; t2 = t1; t1 = t0; t0 = xv; }
          else if (xv > t1) { t3 = t2; t2 = t1; t1 = xv; }
          else if (xv > t2) { t3 = t2; t2 = xv; }
          else              { t3 = xv; }
        }
      }
    }
    thrl[tid] = t3;
  }
  __syncthreads();

  // (3) ballot masks per 64-col block
  #pragma unroll
  for (int i = 0; i < 4; ++i) {
    #pragma unroll
    for (int q = 0; q < 4; ++q) {
      const int rloc = wr * 64 + i * 16 + lg * 4 + q;
      const float th = thrl[rloc];
      unsigned long long bal[4];
      #pragma unroll
      for (int j = 0; j < 4; ++j) bal[j] = __ballot(mval(i, j, q) >= th);
      if (l15 == 0) {
        unsigned long long m = 0;
        #pragma unroll
        for (int j = 0; j < 4; ++j)
          m |= ((bal[j] >> (lg * 16)) & 0xFFFFull) << (j * 16);
        mlds[rloc * 4 + wc] = m;
      }
    }
  }
  __syncthreads();

  // (4) per-row outputs
  if (tid < 128) {
    const int rn = rh * 128 + tid;
    if (rn < TT) {
      const size_t r = (size_t)bj * TT + rn;
      unsigned long long m0 = mlds[tid * 4 + 0], m1 = mlds[tid * 4 + 1],
                         m2 = mlds[tid * 4 + 2], m3 = mlds[tid * 4 + 3];
      int deg = __popcll(m0) + __popcll(m1) + __popcll(m2) + __popcll(m3);
      dis_o[r] = rsqrtf((float)deg);
      deg_o[r] = (unsigned char)((deg > 255) ? 255 : deg);
      mask_o[r * 4 + 0] = m0;
      mask_o[r * 4 + 1] = m1;
      mask_o[r * 4 + 2] = m2;
      mask_o[r * 4 + 3] = m3;
      unsigned long long nbv = 0;
      int cnt = 0;
      #pragma unroll
      for (int w4 = 0; w4 < 4; ++w4) {
        unsigned long long m = (w4 == 0) ? m0 : (w4 == 1) ? m1 : (w4 == 2) ? m2 : m3;
        while (m && cnt < 8) {
          int b = __ffsll(m) - 1;
          m &= m - 1;
          nbv |= ((unsigned long long)(w4 * 64 + b)) << (8 * cnt);
          ++cnt;
        }
      }
      *reinterpret_cast<unsigned long long*>(nbr_o + r * 8) = nbv;
    }
  }
}

// ---------- K1: u,v GEMM; LDS-transposed coalesced store epilogue ----------
#define TST 136   // transpose tile stride (shorts); 272B rows, 16B-aligned
__launch_bounds__(256, 4)
__global__ void k_uv(const _Float16* __restrict__ xqh, const _Float16* __restrict__ wcp,
                     const float* __restrict__ bu, const float* __restrict__ bv,
                     unsigned short* __restrict__ uo, unsigned short* __restrict__ vo) {
  __shared__ __align__(16) char LB2[128 * TST * 2];   // 34816B >= staging 32768B
  _Float16* SA = (_Float16*)LB2;                      // 16 KB: 128 A rows x 64
  _Float16* SB = (_Float16*)(LB2 + 16384);            // 16 KB: 128 W rows x 64
  const int ct = blockIdx.x;                     // 0..3
  const int m0 = blockIdx.y * 128;               // padded flat row base
  const int tid = threadIdx.x, lane = tid & 63, wid = tid >> 6;
  const int rm = wid * 32;
  const int l15 = lane & 15, lg = lane >> 4;

  const float* bsrc = (ct < 2) ? bu : bv;
  unsigned short* osrc = (ct < 2) ? uo : vo;
  const int cb = (ct & 1) * 128;

  f32x4 acc[2][8];
  #pragma unroll
  for (int i = 0; i < 2; i++)
    #pragma unroll
    for (int j = 0; j < 8; j++) acc[i][j] = (f32x4){0.f, 0.f, 0.f, 0.f};

  for (int ks = 0; ks < 4; ++ks) {
    #pragma unroll
    for (int c = 0; c < 8; ++c) {
      int ch = wid * 8 + c;
      int half = ch >> 4;
      int rows0 = (ch & 15) * 8;
      const _Float16* g = half
        ? wcp + ((size_t)ks * 512 + ct * 128 + rows0) * 64 + lane * 8
        : xqh + ((size_t)ks * FR  + m0       + rows0) * 64 + lane * 8;
      gld16(g, (half ? SB : SA) + rows0 * 64);
    }
    __syncthreads();
    #pragma unroll
    for (int kh = 0; kh < 2; ++kh) {
      f16x8 af[2];
      #pragma unroll
      for (int i = 0; i < 2; ++i) {
        int rl = rm + i * 16 + l15;
        af[i] = *reinterpret_cast<const f16x8*>(&SA[rl * 64 + ((kh * 4 + lg) ^ (rl & 7)) * 8]);
      }
      #pragma unroll
      for (int jh = 0; jh < 2; ++jh) {           // split: only 4 bfv live
        f16x8 bfv[4];
        #pragma unroll
        for (int j = 0; j < 4; ++j) {
          int rl = (jh * 4 + j) * 16 + l15;
          bfv[j] = *reinterpret_cast<const f16x8*>(&SB[rl * 64 + ((kh * 4 + lg) ^ (rl & 7)) * 8]);
        }
        #pragma unroll
        for (int i = 0; i < 2; ++i)
          #pragma unroll
          for (int j = 0; j < 4; ++j)
            acc[i][jh * 4 + j] =
              __builtin_amdgcn_mfma_f32_16x16x32_f16(af[i], bfv[j], acc[i][jh * 4 + j], 0, 0, 0);
      }
    }
    __syncthreads();
  }

  float bias[8];
  #pragma unroll
  for (int j = 0; j < 8; ++j) bias[j] = bsrc[cb + j * 16 + l15];

  // transpose through LDS -> coalesced 16B stores
  unsigned short* T = (unsigned short*)LB2;      // [128][TST]
  #pragma unroll
  for (int i = 0; i < 2; ++i) {
    #pragma unroll
    for (int q = 0; q < 4; ++q) {
      int row = rm + i * 16 + lg * 4 + q;        // 0..127
      #pragma unroll
      for (int j = 0; j < 8; ++j)
        T[row * TST + j * 16 + l15] = f2bf(acc[i][j][q] + bias[j]);
    }
  }
  __syncthreads();
  {
    const int row = tid >> 1, half = tid & 1;
    const int gf = m0 + row;
    const int t = gf & 255, bj = gf >> 8;
    if (t < TT) {
      size_t gm = (size_t)bj * TT + t;
      const unsigned short* src = &T[row * TST + half * 64];
      unsigned short* dst = osrc + gm * CC + cb + half * 64;
      #pragma unroll
      for (int e = 0; e < 8; ++e)
        *reinterpret_cast<uint4*>(dst + e * 8) =
          *reinterpret_cast<const uint4*>(src + e * 8);
    }
  }
}

// ---------- K3b: h = norm_adj @ v + u  (list gather: independent loads) ----------
__launch_bounds__(512)
__global__ void k_agg(const unsigned char* __restrict__ nbr,
                      const unsigned char* __restrict__ degv,
                      const unsigned long long* __restrict__ mask,
                      const float* __restrict__ dis,
                      const unsigned short* __restrict__ u,
                      const unsigned short* __restrict__ v,
                      unsigned short* __restrict__ h,
                      float* __restrict__ p1, float* __restrict__ p2) {
  __shared__ float dis_l[256];
  const int bj = blockIdx.x;
  const int tid = threadIdx.x, lane = tid & 63, wid = tid >> 6;
  if (tid < TT) dis_l[tid] = dis[(size_t)bj * TT + tid];
  __syncthreads();
  const int start = blockIdx.y * 122;
  const int cnt = blockIdx.y ? (TT - 122) : 122;
  const size_t pbase = (size_t)bj * TT;
  const int co = lane * 4;
  for (int rl = wid; rl < cnt; rl += 8) {
    const int t = start + rl;
    const size_t r = pbase + t;
    const float dr = dis_l[t];
    const int dg = degv[r];
    const unsigned long long nb = *reinterpret_cast<const unsigned long long*>(nbr + r * 8);
    ushort4 uu = *reinterpret_cast<const ushort4*>(u + r * CC + co);
    float a0 = bf2f(uu.x), a1 = bf2f(uu.y), a2 = bf2f(uu.z), a3 = bf2f(uu.w);
    if (dg <= 8) {
      const int i0 = (int)(nb & 255), i1 = (int)((nb >> 8) & 255),
                i2 = (int)((nb >> 16) & 255), i3 = (int)((nb >> 24) & 255);
      ushort4 w0v = *reinterpret_cast<const ushort4*>(v + (pbase + i0) * CC + co);
      ushort4 w1v = *reinterpret_cast<const ushort4*>(v + (pbase + i1) * CC + co);
      ushort4 w2v = *reinterpret_cast<const ushort4*>(v + (pbase + i2) * CC + co);
      ushort4 w3v = *reinterpret_cast<const ushort4*>(v + (pbase + i3) * CC + co);
      const float w0 = dr * dis_l[i0], w1 = dr * dis_l[i1],
                  w2 = dr * dis_l[i2], w3 = dr * dis_l[i3];
      a0 = __builtin_fmaf(w0, bf2f(w0v.x), a0); a1 = __builtin_fmaf(w0, bf2f(w0v.y), a1);
      a2 = __builtin_fmaf(w0, bf2f(w0v.z), a2); a3 = __builtin_fmaf(w0, bf2f(w0v.w), a3);
      a0 = __builtin_fmaf(w1, bf2f(w1v.x), a0); a1 = __builtin_fmaf(w1, bf2f(w1v.y), a1);
      a2 = __builtin_fmaf(w1, bf2f(w1v.z), a2); a3 = __builtin_fmaf(w1, bf2f(w1v.w), a3);
      a0 = __builtin_fmaf(w2, bf2f(w2v.x), a0); a1 = __builtin_fmaf(w2, bf2f(w2v.y), a1);
      a2 = __builtin_fmaf(w2, bf2f(w2v.z), a2); a3 = __builtin_fmaf(w2, bf2f(w2v.w), a3);
      a0 = __builtin_fmaf(w3, bf2f(w3v.x), a0); a1 = __builtin_fmaf(w3, bf2f(w3v.y), a1);
      a2 = __builtin_fmaf(w3, bf2f(w3v.z), a2); a3 = __builtin_fmaf(w3, bf2f(w3v.w), a3);
      #pragma unroll
      for (int e = 4; e < 8; ++e) {
        if (e < dg) {
          const int ix = (int)((nb >> (8 * e)) & 255);
          const float we = dr * dis_l[ix];
          ushort4 vv = *reinterpret_cast<const ushort4*>(v + (pbase + ix) * CC + co);
          a0 = __builtin_fmaf(we, bf2f(vv.x), a0); a1 = __builtin_fmaf(we, bf2f(vv.y), a1);
          a2 = __builtin_fmaf(we, bf2f(vv.z), a2); a3 = __builtin_fmaf(we, bf2f(vv.w), a3);
        }
      }
    } else {                                     // rare tie overflow: mask decode
      #pragma unroll
      for (int w4 = 0; w4 < 4; ++w4) {
        unsigned long long m = mask[r * 4 + w4];
        while (m) {
          int i = __ffsll(m) - 1;
          m &= m - 1;
          int idx = w4 * 64 + i;
          float w = dr * dis_l[idx];
          ushort4 vv = *reinterpret_cast<const ushort4*>(v + (pbase + idx) * CC + co);
          a0 = __builtin_fmaf(w, bf2f(vv.x), a0);
          a1 = __builtin_fmaf(w, bf2f(vv.y), a1);
          a2 = __builtin_fmaf(w, bf2f(vv.z), a2);
          a3 = __builtin_fmaf(w, bf2f(vv.w), a3);
        }
      }
    }
    ushort4 hh;
    hh.x = f2bf(a0); hh.y = f2bf(a1); hh.z = f2bf(a2); hh.w = f2bf(a3);
    *reinterpret_cast<ushort4*>(h + r * CC + co) = hh;
    float s1 = a0 + a1 + a2 + a3;
    float s2 = a0*a0 + a1*a1 + a2*a2 + a3*a3;
    #pragma unroll
    for (int off = 1; off < 64; off <<= 1) { s1 += __shfl_xor(s1, off); s2 += __shfl_xor(s2, off); }
    if (lane == 0) { p1[r] = s1; p2[r] = s2; }
  }
}

// ---------- K4: BN stats per t -> scale/shift ----------
__global__ void k_bnstat(const float* __restrict__ p1, const float* __restrict__ p2,
                         const float* __restrict__ gamma, const float* __restrict__ beta,
                         float* __restrict__ scale, float* __restrict__ shift) {
  __shared__ float sA[256], sB[256];
  const int t = blockIdx.x;
  const int tid = threadIdx.x;
  float a = 0.f, b2 = 0.f;
  for (int bj = tid; bj < BJC; bj += 256) {
    a  += p1[bj * TT + t];
    b2 += p2[bj * TT + t];
  }
  sA[tid] = a; sB[tid] = b2;
  __syncthreads();
  for (int s = 128; s > 0; s >>= 1) {
    if (tid < s) { sA[tid] += sA[tid + s]; sB[tid] += sB[tid + s]; }
    __syncthreads();
  }
  if (tid == 0) {
    const float invN = 1.0f / (float)(BJC * CC);
    float mean = sA[0] * invN;
    float var  = sB[0] * invN - mean * mean;
    float sc   = rsqrtf(var + 1e-5f) * gamma[t];
    scale[t] = sc;
    shift[t] = beta[t] - mean * sc;
  }
}

// ---------- K5: out = relu(xqh + h*scale + shift), 8 channels/thread ----------
__launch_bounds__(256)
__global__ void k_out(const _Float16* __restrict__ xqh, const unsigned short* __restrict__ h,
                      const float* __restrict__ scale, const float* __restrict__ shift,
                      float* __restrict__ out) {
  int gth = blockIdx.x * 256 + threadIdx.x;      // one 8-channel unit per thread
  if (gth >= MM * 32) return;
  int c8   = gth & 31;
  int rowx = gth >> 5;                           // (b*TT + t)*JJ + j
  int b   = rowx / (TT*JJ);
  int rem = rowx - b*(TT*JJ);
  int t   = rem / JJ;
  int j   = rem - t*JJ;
  int bj  = b * JJ + j;
  const int ks = c8 >> 3, un = c8 & 7, sl = un ^ (t & 7);
  f16x8 xv = *reinterpret_cast<const f16x8*>(
      xqh + ((size_t)ks * FR + (size_t)bj * 256 + t) * 64 + sl * 8);
  const unsigned short* hp = h + ((size_t)bj * TT + t) * CC + c8 * 8;
  ushort4 h0 = *reinterpret_cast<const ushort4*>(hp);
  ushort4 h1 = *reinterpret_cast<const ushort4*>(hp + 4);
  float sc = scale[t], sh = shift[t];
  float4 o0, o1;
  o0.x = fmaxf((float)xv[0] + bf2f(h0.x) * sc + sh, 0.f);
  o0.y = fmaxf((float)xv[1] + bf2f(h0.y) * sc + sh, 0.f);
  o0.z = fmaxf((float)xv[2] + bf2f(h0.z) * sc + sh, 0.f);
  o0.w = fmaxf((float)xv[3] + bf2f(h0.w) * sc + sh, 0.f);
  o1.x = fmaxf((float)xv[4] + bf2f(h1.x) * sc + sh, 0.f);
  o1.y = fmaxf((float)xv[5] + bf2f(h1.y) * sc + sh, 0.f);
  o1.z = fmaxf((float)xv[6] + bf2f(h1.z) * sc + sh, 0.f);
  o1.w = fmaxf((float)xv[7] + bf2f(h1.w) * sc + sh, 0.f);
  float* op = out + (size_t)rowx * CC + c8 * 8;
  *reinterpret_cast<float4*>(op)     = o0;
  *reinterpret_cast<float4*>(op + 4) = o1;
}

extern "C" void kernel_launch(void* const* d_in, const int* in_sizes, int n_in,
                              void* d_out, int out_size, void* d_ws, size_t ws_size,
                              hipStream_t stream) {
  const float* x     = (const float*)d_in[0];
  const float* Wu    = (const float*)d_in[1];
  const float* bu    = (const float*)d_in[2];
  const float* Wv    = (const float*)d_in[3];
  const float* bv    = (const float*)d_in[4];
  const float* gamma = (const float*)d_in[5];
  const float* beta  = (const float*)d_in[6];
  float* out = (float*)d_out;

  char* ws = (char*)d_ws;
  size_t off = 0;
  auto alloc = [&](size_t bytes) -> void* {
    void* p = ws + off;
    off = (off + bytes + 255) & ~(size_t)255;
    return p;
  };
  _Float16* xqh = (_Float16*)alloc((size_t)4 * FR * 64 * 2);      // 71.3MB
  _Float16* xql = (_Float16*)alloc((size_t)4 * FR * 64 * 2);      // 71.3MB
  _Float16* wcp = (_Float16*)alloc((size_t)4 * 512 * 64 * 2);
  float* dis = (float*)alloc((size_t)MM * 4);
  unsigned long long* msk = (unsigned long long*)alloc((size_t)MM * 4 * 8);
  unsigned char* nbr = (unsigned char*)alloc((size_t)MM * 8);
  unsigned char* deg = (unsigned char*)alloc((size_t)MM);
  float* p1    = (float*)alloc((size_t)MM * 4);
  float* p2    = (float*)alloc((size_t)MM * 4);
  float* scale = (float*)alloc(1024);
  float* shift = (float*)alloc(1024);
  unsigned short* u = (unsigned short*)alloc((size_t)MM * CC * 2); // 67.7MB
  unsigned short* v = (unsigned short*)alloc((size_t)MM * CC * 2); // 67.7MB
  // h aliases xql (dead after k_sim; k_agg runs later)
  unsigned short* h = (unsigned short*)xql;

  if (ws_size < off) {
    hipMemsetAsync(d_out, 0, (size_t)out_size * 4, stream);
    return;
  }

  k_prep_w<<<dim3(512/4), dim3(256), 0, stream>>>(Wu, Wv, wcp);
  k_prep_x<<<dim3(MM/4), dim3(256), 0, stream>>>(x, xqh, xql);
  k_sim  <<<dim3(BJC*2), dim3(512), 0, stream>>>(xqh, xql, dis, msk, nbr, deg);
  k_uv   <<<dim3(4, FR/128), dim3(256), 0, stream>>>(xqh, wcp, bu, bv, u, v);
  k_agg  <<<dim3(BJC, 2), dim3(512), 0, stream>>>(nbr, deg, msk, dis, u, v, h, p1, p2);
  k_bnstat<<<dim3(TT), dim3(256), 0, stream>>>(p1, p2, gamma, beta, scale, shift);
  k_out  <<<dim3((MM*32 + 255)/256), dim3(256), 0, stream>>>(xqh, h, scale, shift, out);
}

// Round 20
// 319.954 us; speedup vs baseline: 1.0457x; 1.0457x over previous
//
#include <hip/hip_runtime.h>

#define BB 32
#define TT 243
#define JJ 17
#define CC 256
#define BJC (BB*JJ)          // 544
#define MM (BJC*TT)          // 132192 rows (compact: r = bj*TT + t)
#define FR (BJC*256)         // 139264 padded flat rows: flat = bj*256 + t
#define NEG_INF (-3.0e38f)

typedef __attribute__((ext_vector_type(8))) short bf16x8;
typedef __attribute__((ext_vector_type(4))) float f32x4;
typedef __attribute__((ext_vector_type(8))) _Float16 f16x8;
typedef __attribute__((ext_vector_type(4))) _Float16 f16x4;

__device__ __forceinline__ unsigned short f2bf(float f) {
  unsigned int u = __float_as_uint(f);
  u = (u + 0x7fffu + ((u >> 16) & 1u)) >> 16;   // RNE
  return (unsigned short)u;
}
__device__ __forceinline__ float bf2f(unsigned short s) {
  return __uint_as_float(((unsigned int)s) << 16);
}

// async global->LDS, 16B per lane: lds dest = uniform base + lane*16
__device__ __forceinline__ void gld16(const void* g, void* l) {
  __builtin_amdgcn_global_load_lds(
      (__attribute__((address_space(1))) void*)(g),
      (__attribute__((address_space(3))) void*)(l), 16, 0, 0);
}

// ---------- K0a: W_u,W_v f32 [C,C] -> wcp f16 [4 ksteps][512][64] (swizzled) ----------
__launch_bounds__(256)
__global__ void k_prep_w(const float* __restrict__ Wu, const float* __restrict__ Wv,
                         _Float16* __restrict__ wcp) {
  const int r = blockIdx.x * 4 + (threadIdx.x >> 6);   // 0..511
  const int l = threadIdx.x & 63;
  const float* src = ((r < CC) ? (Wu + (size_t)r * CC) : (Wv + (size_t)(r - CC) * CC)) + l * 4;
  float4 v = *reinterpret_cast<const float4*>(src);
  f16x4 hv = (f16x4){(_Float16)v.x, (_Float16)v.y, (_Float16)v.z, (_Float16)v.w};
  const int ks = l >> 4;                 // k-plane 0..3 (64 f16 each)
  const int u  = (l & 15) >> 1;          // 16B unit 0..7
  const int s  = u ^ (r & 7);            // bank swizzle slot
  *reinterpret_cast<f16x4*>(wcp + ((size_t)ks * 512 + r) * 64 + s * 8 + (l & 1) * 4) = hv;
}

// ---------- K0b: x -> xqh/xql (f16 hi + residual lo), panel-padded flat layout ----------
__launch_bounds__(256)
__global__ void k_prep_x(const float* __restrict__ x,
                         _Float16* __restrict__ xqh, _Float16* __restrict__ xql) {
  const int r = blockIdx.x * 4 + (threadIdx.x >> 6);   // compact row 0..MM-1
  const int l = threadIdx.x & 63;
  const int bj = r / TT, t = r - bj * TT;
  const int b = bj / JJ, j = bj - b * JJ;
  float4 v = *reinterpret_cast<const float4*>(
      x + ((size_t)(b * TT + t) * JJ + j) * CC + l * 4);
  _Float16 h0 = (_Float16)v.x, h1 = (_Float16)v.y, h2 = (_Float16)v.z, h3 = (_Float16)v.w;
  f16x4 hv = (f16x4){h0, h1, h2, h3};
  f16x4 lv = (f16x4){(_Float16)(v.x - (float)h0), (_Float16)(v.y - (float)h1),
                     (_Float16)(v.z - (float)h2), (_Float16)(v.w - (float)h3)};
  const int fr = bj * 256 + t;            // padded flat row
  const int ks = l >> 4;
  const int u  = (l & 15) >> 1;
  const int s  = u ^ (t & 7);             // == fr&7 since bj*256 % 8 == 0
  const size_t off = ((size_t)ks * FR + fr) * 64 + s * 8 + (l & 1) * 4;
  *reinterpret_cast<f16x4*>(xqh + off) = hv;
  *reinterpret_cast<f16x4*>(xql + off) = lv;
}

// ---------- K2: sim + top-k fused, per bj row-half block (XCD-paired) ----------
// Pass-major MFMA order (hh x16, hl x16, lh x16): 16 independent MFMAs between
// accumulator reuses; per-accumulator order preserved -> bitwise identical.
__launch_bounds__(512, 4)
__global__ void k_sim(const _Float16* __restrict__ xqh, const _Float16* __restrict__ xql,
                      float* __restrict__ dis_o,
                      unsigned long long* __restrict__ mask_o,
                      unsigned char* __restrict__ nbr_o,
                      unsigned char* __restrict__ deg_o) {
  __shared__ __align__(16) char LB[65536];
  _Float16* Sh = (_Float16*)LB;                 // 32 KB
  _Float16* Sl = (_Float16*)(LB + 32768);       // 32 KB
  const int bid = blockIdx.x;
  const int g = bid >> 4, s_ = bid & 15;
  const int bj = g * 8 + (s_ & 7);              // 544 = 68*8 -> bijective
  const int rh = s_ >> 3;                       // row half 0/1
  const int tid = threadIdx.x, lane = tid & 63, wid = tid >> 6;
  const int wr = wid >> 2, wc = wid & 3;        // wave tile: 64 rows x 64 cols
  const int rowbase = rh * 128 + wr * 64;
  const int l15 = lane & 15, lg = lane >> 4;
  const size_t rb = (size_t)bj * 256;
  const size_t lsrc = (size_t)(lane >> 3) * 64 + (lane & 7) * 8;

  const int ra0 = rowbase + l15;
  const int ca0 = wc * 64 + l15;
  const int offA0 = ra0 * 64 + (lg ^ (ra0 & 7)) * 8;   // + i*1024
  const int offB0 = ca0 * 64 + (lg ^ (ca0 & 7)) * 8;   // + j*1024

  f32x4 acc[4][4];
  #pragma unroll
  for (int i = 0; i < 4; i++)
    #pragma unroll
    for (int j = 0; j < 4; j++) acc[i][j] = (f32x4){0.f, 0.f, 0.f, 0.f};

  for (int ks = 0; ks < 4; ++ks) {
    {
      const _Float16* ph = xqh + ((size_t)ks * FR + rb) * 64;
      const _Float16* pl = xql + ((size_t)ks * FR + rb) * 64;
      #pragma unroll
      for (int c = 0; c < 4; ++c) {
        const int row0 = (wid * 4 + c) * 8;
        gld16(ph + (size_t)row0 * 64 + lsrc, Sh + row0 * 64);
        gld16(pl + (size_t)row0 * 64 + lsrc, Sl + row0 * 64);
      }
    }
    __syncthreads();
    #pragma unroll
    for (int kh = 0; kh < 2; ++kh) {
      const int kx = kh ? 32 : 0;
      f16x8 ah[4], al[4], bh[4], bl[4];
      #pragma unroll
      for (int j = 0; j < 4; ++j) {
        bh[j] = *reinterpret_cast<const f16x8*>(&Sh[(offB0 + j * 1024) ^ kx]);
        bl[j] = *reinterpret_cast<const f16x8*>(&Sl[(offB0 + j * 1024) ^ kx]);
      }
      #pragma unroll
      for (int i = 0; i < 4; ++i) {
        ah[i] = *reinterpret_cast<const f16x8*>(&Sh[(offA0 + i * 1024) ^ kx]);
        al[i] = *reinterpret_cast<const f16x8*>(&Sl[(offA0 + i * 1024) ^ kx]);
      }
      #pragma unroll
      for (int i = 0; i < 4; ++i)
        #pragma unroll
        for (int j = 0; j < 4; ++j)
          acc[i][j] = __builtin_amdgcn_mfma_f32_16x16x32_f16(ah[i], bh[j], acc[i][j], 0, 0, 0);
      #pragma unroll
      for (int i = 0; i < 4; ++i)
        #pragma unroll
        for (int j = 0; j < 4; ++j)
          acc[i][j] = __builtin_amdgcn_mfma_f32_16x16x32_f16(ah[i], bl[j], acc[i][j], 0, 0, 0);
      #pragma unroll
      for (int i = 0; i < 4; ++i)
        #pragma unroll
        for (int j = 0; j < 4; ++j)
          acc[i][j] = __builtin_amdgcn_mfma_f32_16x16x32_f16(al[i], bh[j], acc[i][j], 0, 0, 0);
    }
    __syncthreads();                            // also frees LB for the epilogue
  }

  // ---- fused top-k epilogue ----
  float* top4 = (float*)LB;                              // [128][4 wc][4]  8 KB
  unsigned long long* mlds = (unsigned long long*)(LB + 8192);  // [128][4]  4 KB
  float* thrl = (float*)(LB + 8192 + 4096);              // [128]           512 B

  auto mval = [&](int i, int j, int q) -> float {
    float x = acc[i][j][q];
    if (wc == 3 && j == 3 && l15 >= 3) x = NEG_INF;
    return x;
  };

  // (1) per-wave top-4 per row
  #pragma unroll
  for (int i = 0; i < 4; ++i) {
    #pragma unroll
    for (int q = 0; q < 4; ++q) {
      float v0 = mval(i, 0, q), v1 = mval(i, 1, q),
            v2 = mval(i, 2, q), v3 = mval(i, 3, q);
      { float mx, mn;
        mx=fmaxf(v0,v1); mn=fminf(v0,v1); v0=mx; v1=mn;
        mx=fmaxf(v2,v3); mn=fminf(v2,v3); v2=mx; v3=mn;
        mx=fmaxf(v0,v2); mn=fminf(v0,v2); v0=mx; v2=mn;
        mx=fmaxf(v1,v3); mn=fminf(v1,v3); v1=mx; v3=mn;
        mx=fmaxf(v1,v2); mn=fminf(v1,v2); v1=mx; v2=mn; }
      #pragma unroll
      for (int off = 1; off < 16; off <<= 1) {   // 16-lane butterfly
        float b0 = __shfl_xor(v0, off), b1 = __shfl_xor(v1, off),
              b2 = __shfl_xor(v2, off), b3 = __shfl_xor(v3, off);
        float t0 = fmaxf(v0, b3), t1 = fmaxf(v1, b2),
              t2 = fmaxf(v2, b1), t3 = fmaxf(v3, b0);
        float mx, mn;
        mx=fmaxf(t0,t2); mn=fminf(t0,t2); t0=mx; t2=mn;
        mx=fmaxf(t1,t3); mn=fminf(t1,t3); t1=mx; t3=mn;
        mx=fmaxf(t0,t1); mn=fminf(t0,t1); t0=mx; t1=mn;
        mx=fmaxf(t2,t3); mn=fminf(t2,t3); t2=mx; t3=mn;
        v0=t0; v1=t1; v2=t2; v3=t3;
      }
      if (l15 == 0) {
        int rloc = wr * 64 + i * 16 + lg * 4 + q;
        float* d = &top4[(rloc * 4 + wc) * 4];
        d[0] = v0; d[1] = v1; d[2] = v2; d[3] = v3;
      }
    }
  }
  __syncthreads();

  // (2) merge 4 wave-quads -> thr per row
  if (tid < 128) {
    float t0 = NEG_INF, t1 = NEG_INF, t2 = NEG_INF, t3 = NEG_INF;
    #pragma unroll
    for (int w = 0; w < 4; ++w) {
      #pragma unroll
      for (int e = 0; e < 4; ++e) {
        float xv = top4[(tid * 4 + w) * 4 + e];
        if (xv > t3) {
          if (xv > t0)      { t3 = t2; t2 = t1; t1 = t0; t0 = xv; }
          else if (xv > t1) { t3 = t2; t2 = t1; t1 = xv; }
          else if (xv > t2) { t3 = t2; t2 = xv; }
          else              { t3 = xv; }
        }
      }
    }
    thrl[tid] = t3;
  }
  __syncthreads();

  // (3) ballot masks per 64-col block
  #pragma unroll
  for (int i = 0; i < 4; ++i) {
    #pragma unroll
    for (int q = 0; q < 4; ++q) {
      const int rloc = wr * 64 + i * 16 + lg * 4 + q;
      const float th = thrl[rloc];
      unsigned long long bal[4];
      #pragma unroll
      for (int j = 0; j < 4; ++j) bal[j] = __ballot(mval(i, j, q) >= th);
      if (l15 == 0) {
        unsigned long long m = 0;
        #pragma unroll
        for (int j = 0; j < 4; ++j)
          m |= ((bal[j] >> (lg * 16)) & 0xFFFFull) << (j * 16);
        mlds[rloc * 4 + wc] = m;
      }
    }
  }
  __syncthreads();

  // (4) per-row outputs
  if (tid < 128) {
    const int rn = rh * 128 + tid;
    if (rn < TT) {
      const size_t r = (size_t)bj * TT + rn;
      unsigned long long m0 = mlds[tid * 4 + 0], m1 = mlds[tid * 4 + 1],
                         m2 = mlds[tid * 4 + 2], m3 = mlds[tid * 4 + 3];
      int deg = __popcll(m0) + __popcll(m1) + __popcll(m2) + __popcll(m3);
      dis_o[r] = rsqrtf((float)deg);
      deg_o[r] = (unsigned char)((deg > 255) ? 255 : deg);
      mask_o[r * 4 + 0] = m0;
      mask_o[r * 4 + 1] = m1;
      mask_o[r * 4 + 2] = m2;
      mask_o[r * 4 + 3] = m3;
      unsigned long long nbv = 0;
      int cnt = 0;
      #pragma unroll
      for (int w4 = 0; w4 < 4; ++w4) {
        unsigned long long m = (w4 == 0) ? m0 : (w4 == 1) ? m1 : (w4 == 2) ? m2 : m3;
        while (m && cnt < 8) {
          int b = __ffsll(m) - 1;
          m &= m - 1;
          nbv |= ((unsigned long long)(w4 * 64 + b)) << (8 * cnt);
          ++cnt;
        }
      }
      *reinterpret_cast<unsigned long long*>(nbr_o + r * 8) = nbv;
    }
  }
}

// ---------- K1: u,v = x @ [Wu;Wv]^T + b  (jh-split, direct stores; r18 form) ----------
__launch_bounds__(256, 4)
__global__ void k_uv(const _Float16* __restrict__ xqh, const _Float16* __restrict__ wcp,
                     const float* __restrict__ bu, const float* __restrict__ bv,
                     unsigned short* __restrict__ uo, unsigned short* __restrict__ vo) {
  __shared__ _Float16 S[2][128][64];             // A rows, B(weight) rows
  const int ct = blockIdx.x;                     // 0..3
  const int m0 = blockIdx.y * 128;               // padded flat row base
  const int tid = threadIdx.x, lane = tid & 63, wid = tid >> 6;
  const int rm = wid * 32;
  const int l15 = lane & 15, lg = lane >> 4;

  const float* bsrc = (ct < 2) ? bu : bv;
  unsigned short* osrc = (ct < 2) ? uo : vo;
  const int cb = (ct & 1) * 128;

  f32x4 acc[2][8];
  #pragma unroll
  for (int i = 0; i < 2; i++)
    #pragma unroll
    for (int j = 0; j < 8; j++) acc[i][j] = (f32x4){0.f, 0.f, 0.f, 0.f};

  for (int ks = 0; ks < 4; ++ks) {
    #pragma unroll
    for (int c = 0; c < 8; ++c) {
      int ch = wid * 8 + c;
      int half = ch >> 4;
      int rows0 = (ch & 15) * 8;
      const _Float16* g = half
        ? wcp + ((size_t)ks * 512 + ct * 128 + rows0) * 64 + lane * 8
        : xqh + ((size_t)ks * FR  + m0       + rows0) * 64 + lane * 8;
      gld16(g, &S[half][rows0][0]);
    }
    __syncthreads();
    #pragma unroll
    for (int kh = 0; kh < 2; ++kh) {
      f16x8 af[2];
      #pragma unroll
      for (int i = 0; i < 2; ++i) {
        int rl = rm + i * 16 + l15;
        af[i] = *reinterpret_cast<const f16x8*>(&S[0][rl][((kh * 4 + lg) ^ (rl & 7)) * 8]);
      }
      #pragma unroll
      for (int jh = 0; jh < 2; ++jh) {           // split: only 4 bfv live
        f16x8 bfv[4];
        #pragma unroll
        for (int j = 0; j < 4; ++j) {
          int rl = (jh * 4 + j) * 16 + l15;
          bfv[j] = *reinterpret_cast<const f16x8*>(&S[1][rl][((kh * 4 + lg) ^ (rl & 7)) * 8]);
        }
        #pragma unroll
        for (int i = 0; i < 2; ++i)
          #pragma unroll
          for (int j = 0; j < 4; ++j)
            acc[i][jh * 4 + j] =
              __builtin_amdgcn_mfma_f32_16x16x32_f16(af[i], bfv[j], acc[i][jh * 4 + j], 0, 0, 0);
      }
    }
    __syncthreads();
  }

  float bias[8];
  #pragma unroll
  for (int j = 0; j < 8; ++j) bias[j] = bsrc[cb + j * 16 + l15];

  #pragma unroll
  for (int i = 0; i < 2; ++i) {
    #pragma unroll
    for (int q = 0; q < 4; ++q) {
      int gf = m0 + rm + i * 16 + lg * 4 + q;    // padded flat row
      int t = gf & 255, bj = gf >> 8;
      if (t < TT) {
        size_t gm = (size_t)bj * TT + t;         // compact row
        #pragma unroll
        for (int j = 0; j < 8; ++j)
          osrc[gm * CC + cb + j * 16 + l15] = f2bf(acc[i][j][q] + bias[j]);
      }
    }
  }
}

// ---------- K3b: h = norm_adj @ v + u  (list gather: independent loads) ----------
__launch_bounds__(512)
__global__ void k_agg(const unsigned char* __restrict__ nbr,
                      const unsigned char* __restrict__ degv,
                      const unsigned long long* __restrict__ mask,
                      const float* __restrict__ dis,
                      const unsigned short* __restrict__ u,
                      const unsigned short* __restrict__ v,
                      unsigned short* __restrict__ h,
                      float* __restrict__ p1, float* __restrict__ p2) {
  __shared__ float dis_l[256];
  const int bj = blockIdx.x;
  const int tid = threadIdx.x, lane = tid & 63, wid = tid >> 6;
  if (tid < TT) dis_l[tid] = dis[(size_t)bj * TT + tid];
  __syncthreads();
  const int start = blockIdx.y * 122;
  const int cnt = blockIdx.y ? (TT - 122) : 122;
  const size_t pbase = (size_t)bj * TT;
  const int co = lane * 4;
  for (int rl = wid; rl < cnt; rl += 8) {
    const int t = start + rl;
    const size_t r = pbase + t;
    const float dr = dis_l[t];
    const int dg = degv[r];
    const unsigned long long nb = *reinterpret_cast<const unsigned long long*>(nbr + r * 8);
    ushort4 uu = *reinterpret_cast<const ushort4*>(u + r * CC + co);
    float a0 = bf2f(uu.x), a1 = bf2f(uu.y), a2 = bf2f(uu.z), a3 = bf2f(uu.w);
    if (dg <= 8) {
      const int i0 = (int)(nb & 255), i1 = (int)((nb >> 8) & 255),
                i2 = (int)((nb >> 16) & 255), i3 = (int)((nb >> 24) & 255);
      ushort4 w0v = *reinterpret_cast<const ushort4*>(v + (pbase + i0) * CC + co);
      ushort4 w1v = *reinterpret_cast<const ushort4*>(v + (pbase + i1) * CC + co);
      ushort4 w2v = *reinterpret_cast<const ushort4*>(v + (pbase + i2) * CC + co);
      ushort4 w3v = *reinterpret_cast<const ushort4*>(v + (pbase + i3) * CC + co);
      const float w0 = dr * dis_l[i0], w1 = dr * dis_l[i1],
                  w2 = dr * dis_l[i2], w3 = dr * dis_l[i3];
      a0 = __builtin_fmaf(w0, bf2f(w0v.x), a0); a1 = __builtin_fmaf(w0, bf2f(w0v.y), a1);
      a2 = __builtin_fmaf(w0, bf2f(w0v.z), a2); a3 = __builtin_fmaf(w0, bf2f(w0v.w), a3);
      a0 = __builtin_fmaf(w1, bf2f(w1v.x), a0); a1 = __builtin_fmaf(w1, bf2f(w1v.y), a1);
      a2 = __builtin_fmaf(w1, bf2f(w1v.z), a2); a3 = __builtin_fmaf(w1, bf2f(w1v.w), a3);
      a0 = __builtin_fmaf(w2, bf2f(w2v.x), a0); a1 = __builtin_fmaf(w2, bf2f(w2v.y), a1);
      a2 = __builtin_fmaf(w2, bf2f(w2v.z), a2); a3 = __builtin_fmaf(w2, bf2f(w2v.w), a3);
      a0 = __builtin_fmaf(w3, bf2f(w3v.x), a0); a1 = __builtin_fmaf(w3, bf2f(w3v.y), a1);
      a2 = __builtin_fmaf(w3, bf2f(w3v.z), a2); a3 = __builtin_fmaf(w3, bf2f(w3v.w), a3);
      #pragma unroll
      for (int e = 4; e < 8; ++e) {
        if (e < dg) {
          const int ix = (int)((nb >> (8 * e)) & 255);
          const float we = dr * dis_l[ix];
          ushort4 vv = *reinterpret_cast<const ushort4*>(v + (pbase + ix) * CC + co);
          a0 = __builtin_fmaf(we, bf2f(vv.x), a0); a1 = __builtin_fmaf(we, bf2f(vv.y), a1);
          a2 = __builtin_fmaf(we, bf2f(vv.z), a2); a3 = __builtin_fmaf(we, bf2f(vv.w), a3);
        }
      }
    } else {                                     // rare tie overflow: mask decode
      #pragma unroll
      for (int w4 = 0; w4 < 4; ++w4) {
        unsigned long long m = mask[r * 4 + w4];
        while (m) {
          int i = __ffsll(m) - 1;
          m &= m - 1;
          int idx = w4 * 64 + i;
          float w = dr * dis_l[idx];
          ushort4 vv = *reinterpret_cast<const ushort4*>(v + (pbase + idx) * CC + co);
          a0 = __builtin_fmaf(w, bf2f(vv.x), a0);
          a1 = __builtin_fmaf(w, bf2f(vv.y), a1);
          a2 = __builtin_fmaf(w, bf2f(vv.z), a2);
          a3 = __builtin_fmaf(w, bf2f(vv.w), a3);
        }
      }
    }
    ushort4 hh;
    hh.x = f2bf(a0); hh.y = f2bf(a1); hh.z = f2bf(a2); hh.w = f2bf(a3);
    *reinterpret_cast<ushort4*>(h + r * CC + co) = hh;
    float s1 = a0 + a1 + a2 + a3;
    float s2 = a0*a0 + a1*a1 + a2*a2 + a3*a3;
    #pragma unroll
    for (int off = 1; off < 64; off <<= 1) { s1 += __shfl_xor(s1, off); s2 += __shfl_xor(s2, off); }
    if (lane == 0) { p1[r] = s1; p2[r] = s2; }
  }
}

// ---------- K4: BN stats per t -> scale/shift ----------
__global__ void k_bnstat(const float* __restrict__ p1, const float* __restrict__ p2,
                         const float* __restrict__ gamma, const float* __restrict__ beta,
                         float* __restrict__ scale, float* __restrict__ shift) {
  __shared__ float sA[256], sB[256];
  const int t = blockIdx.x;
  const int tid = threadIdx.x;
  float a = 0.f, b2 = 0.f;
  for (int bj = tid; bj < BJC; bj += 256) {
    a  += p1[bj * TT + t];
    b2 += p2[bj * TT + t];
  }
  sA[tid] = a; sB[tid] = b2;
  __syncthreads();
  for (int s = 128; s > 0; s >>= 1) {
    if (tid < s) { sA[tid] += sA[tid + s]; sB[tid] += sB[tid + s]; }
    __syncthreads();
  }
  if (tid == 0) {
    const float invN = 1.0f / (float)(BJC * CC);
    float mean = sA[0] * invN;
    float var  = sB[0] * invN - mean * mean;
    float sc   = rsqrtf(var + 1e-5f) * gamma[t];
    scale[t] = sc;
    shift[t] = beta[t] - mean * sc;
  }
}

// ---------- K5: out = relu(xqh + h*scale + shift), 8 channels/thread ----------
__launch_bounds__(256)
__global__ void k_out(const _Float16* __restrict__ xqh, const unsigned short* __restrict__ h,
                      const float* __restrict__ scale, const float* __restrict__ shift,
                      float* __restrict__ out) {
  int gth = blockIdx.x * 256 + threadIdx.x;      // one 8-channel unit per thread
  if (gth >= MM * 32) return;
  int c8   = gth & 31;
  int rowx = gth >> 5;                           // (b*TT + t)*JJ + j
  int b   = rowx / (TT*JJ);
  int rem = rowx - b*(TT*JJ);
  int t   = rem / JJ;
  int j   = rem - t*JJ;
  int bj  = b * JJ + j;
  const int ks = c8 >> 3, un = c8 & 7, sl = un ^ (t & 7);
  f16x8 xv = *reinterpret_cast<const f16x8*>(
      xqh + ((size_t)ks * FR + (size_t)bj * 256 + t) * 64 + sl * 8);
  const unsigned short* hp = h + ((size_t)bj * TT + t) * CC + c8 * 8;
  ushort4 h0 = *reinterpret_cast<const ushort4*>(hp);
  ushort4 h1 = *reinterpret_cast<const ushort4*>(hp + 4);
  float sc = scale[t], sh = shift[t];
  float4 o0, o1;
  o0.x = fmaxf((float)xv[0] + bf2f(h0.x) * sc + sh, 0.f);
  o0.y = fmaxf((float)xv[1] + bf2f(h0.y) * sc + sh, 0.f);
  o0.z = fmaxf((float)xv[2] + bf2f(h0.z) * sc + sh, 0.f);
  o0.w = fmaxf((float)xv[3] + bf2f(h0.w) * sc + sh, 0.f);
  o1.x = fmaxf((float)xv[4] + bf2f(h1.x) * sc + sh, 0.f);
  o1.y = fmaxf((float)xv[5] + bf2f(h1.y) * sc + sh, 0.f);
  o1.z = fmaxf((float)xv[6] + bf2f(h1.z) * sc + sh, 0.f);
  o1.w = fmaxf((float)xv[7] + bf2f(h1.w) * sc + sh, 0.f);
  float* op = out + (size_t)rowx * CC + c8 * 8;
  *reinterpret_cast<float4*>(op)     = o0;
  *reinterpret_cast<float4*>(op + 4) = o1;
}

extern "C" void kernel_launch(void* const* d_in, const int* in_sizes, int n_in,
                              void* d_out, int out_size, void* d_ws, size_t ws_size,
                              hipStream_t stream) {
  const float* x     = (const float*)d_in[0];
  const float* Wu    = (const float*)d_in[1];
  const float* bu    = (const float*)d_in[2];
  const float* Wv    = (const float*)d_in[3];
  const float* bv    = (const float*)d_in[4];
  const float* gamma = (const float*)d_in[5];
  const float* beta  = (const float*)d_in[6];
  float* out = (float*)d_out;

  char* ws = (char*)d_ws;
  size_t off = 0;
  auto alloc = [&](size_t bytes) -> void* {
    void* p = ws + off;
    off = (off + bytes + 255) & ~(size_t)255;
    return p;
  };
  _Float16* xqh = (_Float16*)alloc((size_t)4 * FR * 64 * 2);      // 71.3MB
  _Float16* xql = (_Float16*)alloc((size_t)4 * FR * 64 * 2);      // 71.3MB
  _Float16* wcp = (_Float16*)alloc((size_t)4 * 512 * 64 * 2);
  float* dis = (float*)alloc((size_t)MM * 4);
  unsigned long long* msk = (unsigned long long*)alloc((size_t)MM * 4 * 8);
  unsigned char* nbr = (unsigned char*)alloc((size_t)MM * 8);
  unsigned char* deg = (unsigned char*)alloc((size_t)MM);
  float* p1    = (float*)alloc((size_t)MM * 4);
  float* p2    = (float*)alloc((size_t)MM * 4);
  float* scale = (float*)alloc(1024);
  float* shift = (float*)alloc(1024);
  unsigned short* u = (unsigned short*)alloc((size_t)MM * CC * 2); // 67.7MB
  unsigned short* v = (unsigned short*)alloc((size_t)MM * CC * 2); // 67.7MB
  // h aliases xql (dead after k_sim; k_agg runs later)
  unsigned short* h = (unsigned short*)xql;

  if (ws_size < off) {
    hipMemsetAsync(d_out, 0, (size_t)out_size * 4, stream);
    return;
  }

  k_prep_w<<<dim3(512/4), dim3(256), 0, stream>>>(Wu, Wv, wcp);
  k_prep_x<<<dim3(MM/4), dim3(256), 0, stream>>>(x, xqh, xql);
  k_sim  <<<dim3(BJC*2), dim3(512), 0, stream>>>(xqh, xql, dis, msk, nbr, deg);
  k_uv   <<<dim3(4, FR/128), dim3(256), 0, stream>>>(xqh, wcp, bu, bv, u, v);
  k_agg  <<<dim3(BJC, 2), dim3(512), 0, stream>>>(nbr, deg, msk, dis, u, v, h, p1, p2);
  k_bnstat<<<dim3(TT), dim3(256), 0, stream>>>(p1, p2, gamma, beta, scale, shift);
  k_out  <<<dim3((MM*32 + 255)/256), dim3(256), 0, stream>>>(xqh, h, scale, shift, out);
}